// Round 2
// baseline (370.844 us; speedup 1.0000x reference)
//
#include <hip/hip_runtime.h>
#include <stdint.h>

#define OBS 15
#define NTOT 50000
#define HDIM 64
#define NPB 16               // neighbors per block (50000 = 3125*16, exact)
#define NBLK_N 3125          // neighbor blocks; block 3125 runs target LSTM
#define ZOFF (OBS * NPB * 8) // ushort index of the 16B zero slot in xbf

typedef __attribute__((ext_vector_type(8))) short short8;
typedef __attribute__((ext_vector_type(4))) float f32x4;
typedef __attribute__((ext_vector_type(2))) unsigned int u32x2;
typedef __attribute__((ext_vector_type(4))) unsigned int u32x4;

static __device__ __forceinline__ unsigned short f2bf(float f) {
  unsigned u = __float_as_uint(f);
  u += 0x7fff + ((u >> 16) & 1);
  return (unsigned short)(u >> 16);
}
static __device__ __forceinline__ float bf2f(unsigned short b) {
  return __uint_as_float(((unsigned)b) << 16);
}
// RNE pack of two f32 -> 2 bf16 in one VALU inst.
static __device__ __forceinline__ unsigned cvtpk_bf16(float lo, float hi) {
  unsigned r;
  asm("v_cvt_pk_bf16_f32 %0, %1, %2" : "=v"(r) : "v"(lo), "v"(hi));
  return r;
}

#if __has_builtin(__builtin_amdgcn_exp2f)
#define EXP2F(x) __builtin_amdgcn_exp2f(x)
#else
#define EXP2F(x) exp2f(x)
#endif
#if __has_builtin(__builtin_amdgcn_rcpf)
#define RCPF(x) __builtin_amdgcn_rcpf(x)
#else
#define RCPF(x) (1.0f / (x))
#endif

static __device__ __forceinline__ float sigm(float x) {
  return RCPF(1.0f + EXP2F(-1.4426950408889634f * x));
}
static __device__ __forceinline__ float tanh_(float x) {
  return 2.0f * RCPF(1.0f + EXP2F(-2.8853900817779268f * x)) - 1.0f;
}

__global__ void k_zero(float* social) {
  social[threadIdx.x] = 0.0f;  // 1024 threads == 16*64 floats
}

#define MFMA_BF16 __builtin_amdgcn_mfma_f32_16x16x32_bf16

// Transposed-MFMA formulation (verified correct in round 1, absmax 0.0):
// A-operand = W_hh rows (gates=M), B-operand = h columns (neighbors=N).
// Each thread owns 4 CONSECUTIVE hidden dims of ONE neighbor -> packed
// ds_write_b64 h-write via v_cvt_pk_bf16_f32.  x*W_ih + bias folded into one
// MFMA per gate quadrant via an 8-row hi/lo scheme (err ~2^-18).
// ROUND-1 LESSON: NPB=32 (two groups) doubled the live accumulator set to
// ~190 regs -> scratch spill in the 15-step loop (WRITE_SIZE 2.2->8.9 MB,
// 3x stall).  NPB=16 keeps the live set ~115 combined regs — round-0 level.
// launch_bounds(256,2): 256-VGPR budget; (256,4) pins arch-VGPRs to 64 and
// spills the persistent fragment set (measured in earlier rounds).
__global__ __launch_bounds__(256, 2)
void k_neigh(
    const float* __restrict__ tgt,   // 15*1*2
    const float* __restrict__ oth,   // 15*N*2
    const int* __restrict__ mask,    // 15*N
    const float* __restrict__ W_ih,  // 256*2
    const float* __restrict__ b_ih,  // 256
    const float* __restrict__ W_hh,  // 256*64
    const float* __restrict__ b_hh,  // 256
    float* __restrict__ social,      // 16*64, pre-zeroed
    float* __restrict__ ht_out)      // 64 (target-LSTM final h)
{
  // [buf][n=16 rows x 128B], bf16 h, XOR-swizzled (bits 4..6 by n&7)
  __shared__ __align__(16) unsigned char hbuf[2][2048];
  // per (t,n): 8 ushorts {x0hi,x0hi,x0lo,x1hi,x1hi,x1lo,1,1} + 16B zero slot
  __shared__ __align__(16) unsigned short xbf[ZOFF + 8];
  __shared__ float xs14[NPB][2];
  __shared__ float tht[HDIM];
  __shared__ float tgb[256];

  const int tid = threadIdx.x;

  if (blockIdx.x == NBLK_N) {
    // ---- target LSTM, fp32 exact; runs concurrently with neighbor blocks ----
    const float bias = b_ih[tid] + b_hh[tid];
    const float wi0 = W_ih[tid * 2], wi1 = W_ih[tid * 2 + 1];
    const float4* Wr = (const float4*)&W_hh[tid * 64];
    if (tid < HDIM) tht[tid] = 0.0f;
    float ct = 0.0f;
    __syncthreads();
    for (int t = 0; t < OBS; ++t) {
      const float x0 = tgt[t * 2], x1 = tgt[t * 2 + 1];
      float acc = bias + x0 * wi0 + x1 * wi1;
#pragma unroll
      for (int k4 = 0; k4 < 16; ++k4) {
        const float4 wv = Wr[k4];
        const float4 hv = *(const float4*)&tht[k4 * 4];
        acc += wv.x * hv.x + wv.y * hv.y + wv.z * hv.z + wv.w * hv.w;
      }
      tgb[tid] = acc;
      __syncthreads();
      if (tid < HDIM) {
        const float cn =
            sigm(tgb[64 + tid]) * ct + sigm(tgb[tid]) * tanh_(tgb[128 + tid]);
        ct = cn;
        tht[tid] = sigm(tgb[192 + tid]) * tanh_(cn);
      }
      __syncthreads();
    }
    if (tid < HDIM) ht_out[tid] = tht[tid];
    return;
  }

  const int l = tid & 63;
  const int w = tid >> 6;   // wave id 0..3 -> owns hidden dims w*16..w*16+15
  const int t15 = l & 15;   // = neighbor for B and D
  const int g4 = l >> 4;    // k-block
  const int n0 = blockIdx.x * NPB;

  // ---- stage x hi/lo MFMA table + last-step raw positions (240 items) ----
  for (int i = tid; i < OBS * NPB; i += 256) {
    const int t = i >> 4, n = i & 15;
    const int gn = n0 + n;
    const float x0 = oth[(t * NTOT + gn) * 2 + 0];
    const float x1 = oth[(t * NTOT + gn) * 2 + 1];
    const unsigned short xh0 = f2bf(x0);
    const unsigned short xl0 = f2bf(x0 - bf2f(xh0));
    const unsigned short xh1 = f2bf(x1);
    const unsigned short xl1 = f2bf(x1 - bf2f(xh1));
    u32x4 d;
    d.x = (unsigned)xh0 | ((unsigned)xh0 << 16);  // k0=x0hi k1=x0hi
    d.y = (unsigned)xl0 | ((unsigned)xh1 << 16);  // k2=x0lo k3=x1hi
    d.z = (unsigned)xh1 | ((unsigned)xl1 << 16);  // k4=x1hi k5=x1lo
    d.w = 0x3F803F80u;                            // k6=1    k7=1
    *(u32x4*)&xbf[i * 8] = d;
    if (t == OBS - 1) { xs14[n][0] = x0; xs14[n][1] = x1; }
  }
  if (tid == 0) {
    u32x4 zz = {0u, 0u, 0u, 0u};
    *(u32x4*)&xbf[ZOFF] = zz;
  }
  // zero h buffer 0: 2048 B
  for (int i = tid; i < 512; i += 256) ((unsigned*)hbuf[0])[i] = 0u;

  // ---- persistent A fragments: W_hh rows, hi/lo split.  A row (l&15) ->
  // gate q*64 + w*16 + t15; k = kt*32 + g4*8 + j.  (Proven indexing.)
  short8 A00, A01, A10, A11, A20, A21, A30, A31;
  short8 L00, L01, L10, L11, L20, L21, L30, L31;
#define LOADW(q, kt, AH, AL)                                                  \
  {                                                                           \
    const float* wp = &W_hh[(q * 64 + w * 16 + t15) * 64 + kt * 32 + g4 * 8]; \
    _Pragma("unroll") for (int j = 0; j < 8; ++j) {                           \
      float wv = wp[j];                                                       \
      unsigned short hi = f2bf(wv);                                           \
      unsigned short lo = f2bf(wv - bf2f(hi));                                \
      AH[j] = (short)hi;                                                      \
      AL[j] = (short)lo;                                                      \
    }                                                                         \
  }
  LOADW(0, 0, A00, L00) LOADW(0, 1, A01, L01)
  LOADW(1, 0, A10, L10) LOADW(1, 1, A11, L11)
  LOADW(2, 0, A20, L20) LOADW(2, 1, A21, L21)
  LOADW(3, 0, A30, L30) LOADW(3, 1, A31, L31)
#undef LOADW

  // ---- A_x fragments (x-part + bias as MFMA).  Only k=0..7 rows nonzero.
  short8 X0, X1, X2, X3;
  {
    u32x4 z4 = {0u, 0u, 0u, 0u};
    X0 = X1 = X2 = X3 = __builtin_bit_cast(short8, z4);
    if (g4 == 0) {
#pragma unroll
      for (int q = 0; q < 4; ++q) {
        const int G = q * 64 + w * 16 + t15;
        const float w0 = W_ih[G * 2 + 0], w1 = W_ih[G * 2 + 1];
        const float bs = b_ih[G] + b_hh[G];
        const unsigned short w0h = f2bf(w0), w0l = f2bf(w0 - bf2f(w0h));
        const unsigned short w1h = f2bf(w1), w1l = f2bf(w1 - bf2f(w1h));
        const unsigned short bh = f2bf(bs), bl = f2bf(bs - bf2f(bh));
        u32x4 d;
        d.x = (unsigned)w0h | ((unsigned)w0l << 16);
        d.y = (unsigned)w0h | ((unsigned)w1h << 16);
        d.z = (unsigned)w1l | ((unsigned)w1h << 16);
        d.w = (unsigned)bh | ((unsigned)bl << 16);
        const short8 v = __builtin_bit_cast(short8, d);
        if (q == 0) X0 = v;
        else if (q == 1) X1 = v;
        else if (q == 2) X2 = v;
        else X3 = v;
      }
    }
  }

  // ---- LDS offsets (bytes), XOR swizzle by n&7 (conflict-free minimum)
  const int swz = (t15 & 7) << 4;
  const int hr0 = t15 * 128 + ((g4 * 16) ^ swz);            // B read, kt=0
  const int hr1 = t15 * 128 + (((g4 * 16) + 64) ^ swz);     // B read, kt=1
  const int hw = t15 * 128 + (((w * 32) + (g4 * 8)) ^ swz); // h write (8B)
  int xo = (g4 == 0) ? (t15 * 8) : ZOFF;     // ushort index into xbf
  const int xst = (g4 == 0) ? (NPB * 8) : 0; // per-step advance

  f32x4 c0 = {0.f, 0.f, 0.f, 0.f};
  const float refx = tgt[(OBS - 1) * 2 + 0];
  const float refy = tgt[(OBS - 1) * 2 + 1];

  __syncthreads();

  for (int t = 0; t < OBS; ++t) {
    const int cur = t & 1, nxt = cur ^ 1;
    const unsigned char* hb = hbuf[cur];
    const short8 Bx0 = *(const short8*)&xbf[xo];
    const short8 B00 = *(const short8*)(hb + hr0);
    const short8 B01 = *(const short8*)(hb + hr1);
    xo += xst;

    const f32x4 z = {0.f, 0.f, 0.f, 0.f};
    f32x4 p0 = MFMA_BF16(X0, Bx0, z, 0, 0, 0);
    f32x4 p1 = MFMA_BF16(X1, Bx0, z, 0, 0, 0);
    f32x4 p2 = MFMA_BF16(X2, Bx0, z, 0, 0, 0);
    f32x4 p3 = MFMA_BF16(X3, Bx0, z, 0, 0, 0);
    p0 = MFMA_BF16(A00, B00, p0, 0, 0, 0);
    p1 = MFMA_BF16(A10, B00, p1, 0, 0, 0);
    p2 = MFMA_BF16(A20, B00, p2, 0, 0, 0);
    p3 = MFMA_BF16(A30, B00, p3, 0, 0, 0);
    p0 = MFMA_BF16(A01, B01, p0, 0, 0, 0);
    p1 = MFMA_BF16(A11, B01, p1, 0, 0, 0);
    p2 = MFMA_BF16(A21, B01, p2, 0, 0, 0);
    p3 = MFMA_BF16(A31, B01, p3, 0, 0, 0);
    p0 = MFMA_BF16(L00, B00, p0, 0, 0, 0);
    p1 = MFMA_BF16(L10, B00, p1, 0, 0, 0);
    p2 = MFMA_BF16(L20, B00, p2, 0, 0, 0);
    p3 = MFMA_BF16(L30, B00, p3, 0, 0, 0);
    p0 = MFMA_BF16(L01, B01, p0, 0, 0, 0);
    p1 = MFMA_BF16(L11, B01, p1, 0, 0, 0);
    p2 = MFMA_BF16(L21, B01, p2, 0, 0, 0);
    p3 = MFMA_BF16(L31, B01, p3, 0, 0, 0);

    if (t < OBS - 1) {
      float hv[4];
#pragma unroll
      for (int r = 0; r < 4; ++r) {
        const float gi = p0[r], gf = p1[r], gg = p2[r], go = p3[r];
        const float cn = sigm(gf) * c0[r] + sigm(gi) * tanh_(gg);
        c0[r] = cn;
        hv[r] = sigm(go) * tanh_(cn);
      }
      u32x2 pk;
      pk.x = cvtpk_bf16(hv[0], hv[1]);
      pk.y = cvtpk_bf16(hv[2], hv[3]);
      *(u32x2*)(hbuf[nxt] + hw) = pk;
      __syncthreads();
    } else {
      // final step: compute h (fp32) and pool directly
      float hv[4];
#pragma unroll
      for (int r = 0; r < 4; ++r) {
        const float gi = p0[r], gf = p1[r], gg = p2[r], go = p3[r];
        const float cn = sigm(gf) * c0[r] + sigm(gi) * tanh_(gg);
        hv[r] = sigm(go) * tanh_(cn);
      }
      const int gn = n0 + t15;
      const float rx = xs14[t15][0] - refx;
      const float ry = xs14[t15][1] - refy;
      bool ok = (fabsf(rx) <= 2.0f) && (fabsf(ry) <= 2.0f);
      const int cx = (int)truncf(rx) + 2;  // cw == 1.0
      const int cy = (int)truncf(ry) + 2;
      ok = ok && (cx >= 0) && (cx < 4) && (cy >= 0) && (cy < 4);
      if (ok && mask[(OBS - 1) * NTOT + gn] != 0) {
        float* sp = &social[(cy * 4 + cx) * HDIM + w * 16 + g4 * 4];
#pragma unroll
        for (int r = 0; r < 4; ++r) atomicAdd(&sp[r], hv[r]);
      }
    }
  }
}

__global__ __launch_bounds__(512) void k_final(
    const float* __restrict__ W1, const float* __restrict__ b1,
    const float* __restrict__ W2, const float* __restrict__ b2,
    const float* __restrict__ Wc, const float* __restrict__ bc,
    const float* __restrict__ social, const float* __restrict__ ht_g,
    float* __restrict__ out)
{
  __shared__ float sv[1024];
  __shared__ float hid[64];
  __shared__ float comb[64];
  __shared__ float ht[64];

  const int tid = threadIdx.x;
  for (int i = tid; i < 1024; i += 512) sv[i] = social[i];
  if (tid < 64) ht[tid] = ht_g[tid];
  __syncthreads();

  const int wv = tid >> 6, ln = tid & 63;
  for (int o = wv; o < 64; o += 8) {
    float p = 0.0f;
#pragma unroll
    for (int it = 0; it < 16; ++it) {
      const int j = it * 64 + ln;
      p += sv[j] * W1[o * 1024 + j];
    }
#pragma unroll
    for (int off = 32; off > 0; off >>= 1) p += __shfl_down(p, off);
    if (ln == 0) hid[o] = fmaxf(p + b1[o], 0.0f);
  }
  __syncthreads();
  for (int o = wv; o < 64; o += 8) {
    float p = hid[ln] * W2[o * 64 + ln];
#pragma unroll
    for (int off = 32; off > 0; off >>= 1) p += __shfl_down(p, off);
    if (ln == 0) comb[o] = ht[o] + p + b2[o];
  }
  __syncthreads();
  if (wv < 2) {
    float p = comb[ln] * Wc[wv * 64 + ln];
#pragma unroll
    for (int off = 32; off > 0; off >>= 1) p += __shfl_down(p, off);
    if (ln == 0) out[wv] = p + bc[wv];
  }
}

extern "C" void kernel_launch(void* const* d_in, const int* in_sizes, int n_in,
                              void* d_out, int out_size, void* d_ws, size_t ws_size,
                              hipStream_t stream) {
  const float* tgt = (const float*)d_in[0];
  const float* oth = (const float*)d_in[1];
  const int* mask = (const int*)d_in[2];
  const float* W_ih = (const float*)d_in[3];
  const float* b_ih = (const float*)d_in[4];
  const float* W_hh = (const float*)d_in[5];
  const float* b_hh = (const float*)d_in[6];
  const float* W1 = (const float*)d_in[7];
  const float* b1 = (const float*)d_in[8];
  const float* W2 = (const float*)d_in[9];
  const float* b2 = (const float*)d_in[10];
  const float* Wc = (const float*)d_in[11];
  const float* bc = (const float*)d_in[12];
  float* social = (float*)d_ws;          // ws[0..1023]
  float* ht = social + 1024;             // ws[1024..1087] (target-LSTM h)
  float* out = (float*)d_out;

  hipLaunchKernelGGL(k_zero, dim3(1), dim3(1024), 0, stream, social);
  hipLaunchKernelGGL(k_neigh, dim3(NBLK_N + 1), dim3(256), 0, stream,
                     tgt, oth, mask, W_ih, b_ih, W_hh, b_hh, social, ht);
  hipLaunchKernelGGL(k_final, dim3(1), dim3(512), 0, stream,
                     W1, b1, W2, b2, Wc, bc, social, ht, out);
}

// Round 3
// 138.578 us; speedup vs baseline: 2.6761x; 2.6761x over previous
//
#include <hip/hip_runtime.h>
#include <stdint.h>

#define OBS 15
#define NTOT 50000
#define HDIM 64
#define NPB 16      // neighbors per block (50000 = 3125 * 16, exact)
#define NBLK_N 3125 // neighbor blocks; block index 3125 runs the target LSTM

typedef __attribute__((ext_vector_type(8))) short short8;
typedef __attribute__((ext_vector_type(4))) float f32x4;

static __device__ __forceinline__ unsigned short f2bf(float f) {
  unsigned u = __float_as_uint(f);
  u += 0x7fff + ((u >> 16) & 1);
  return (unsigned short)(u >> 16);
}
static __device__ __forceinline__ float bf2f(unsigned short b) {
  return __uint_as_float(((unsigned)b) << 16);
}

#if __has_builtin(__builtin_amdgcn_exp2f)
#define EXP2F(x) __builtin_amdgcn_exp2f(x)
#else
#define EXP2F(x) exp2f(x)
#endif
#if __has_builtin(__builtin_amdgcn_rcpf)
#define RCPF(x) __builtin_amdgcn_rcpf(x)
#else
#define RCPF(x) (1.0f / (x))
#endif

static __device__ __forceinline__ float sigm(float x) {
  return RCPF(1.0f + EXP2F(-1.4426950408889634f * x));
}
static __device__ __forceinline__ float tanh_(float x) {
  return 2.0f * RCPF(1.0f + EXP2F(-2.8853900817779268f * x)) - 1.0f;
}

// LDS ushort index: row r (0..15), 8-ushort block cb (0..7), swizzled.
// 16B-aligned blocks; read & write both apply it.
static __device__ __forceinline__ int hidx(int r, int cb) {
  return r * 64 + ((cb ^ (r & 7)) << 3);
}

__global__ void k_zero(float* social) {
  social[threadIdx.x] = 0.0f;  // 1024 threads == 16*64 floats
}

#define MFMA_BF16 __builtin_amdgcn_mfma_f32_16x16x32_bf16

// ROUND-0 PROVEN INNER LOOP (118.5 us, 84 VGPR, 0 bank conflicts) restored
// byte-for-byte.  Rounds 1-2 tried a transposed-MFMA formulation (W as
// A-operand): correct (absmax 0.0) and fewer issued instructions, but the
// per-step latency DOUBLED (370 us total, VALU-busy time unchanged at ~60 us,
// MfmaUtil 17->6.6) for reasons the counters did not isolate — abandoned.
// Kept from rounds 1-2 (independently verified): target-LSTM fused as one
// extra block of this kernel (hidden under the 3125 neighbor blocks), and the
// slimmed k_final.
// launch_bounds(256, 2): min 2 waves/EU -> 256-VGPR budget. Earlier rounds
// proved (256,4)/waves_per_eu(4) pins arch-VGPRs to 64 and spills the
// 64-reg B-fragment set to scratch (168 MB HBM writes/dispatch).
__global__ __launch_bounds__(256, 2)
void k_neigh(
    const float* __restrict__ tgt,   // 15*1*2
    const float* __restrict__ oth,   // 15*N*2
    const int* __restrict__ mask,    // 15*N
    const float* __restrict__ W_ih,  // 256*2
    const float* __restrict__ b_ih,  // 256
    const float* __restrict__ W_hh,  // 256*64
    const float* __restrict__ b_hh,  // 256
    float* __restrict__ social,      // 16*64, pre-zeroed
    float* __restrict__ ht_out)      // 64 (target-LSTM final h)
{
  __shared__ __align__(16) unsigned short h2[2][NPB][HDIM];  // h as bf16
  __shared__ float xs[OBS][NPB][2];
  __shared__ float tht[HDIM];
  __shared__ float tgb[256];

  const int tid = threadIdx.x;

  if (blockIdx.x == NBLK_N) {
    // ---- target LSTM, fp32 exact; runs concurrently with neighbor blocks.
    // Block-uniform branch; all 256 threads reach the barriers.
    const float bias = b_ih[tid] + b_hh[tid];
    const float wi0 = W_ih[tid * 2], wi1 = W_ih[tid * 2 + 1];
    const float4* Wr = (const float4*)&W_hh[tid * 64];
    if (tid < HDIM) tht[tid] = 0.0f;
    float ct = 0.0f;
    __syncthreads();
    for (int t = 0; t < OBS; ++t) {
      const float x0 = tgt[t * 2], x1 = tgt[t * 2 + 1];
      float acc = bias + x0 * wi0 + x1 * wi1;
      // unroll 4 keeps this region's VGPR demand below the main path's 84
#pragma unroll 4
      for (int k4 = 0; k4 < 16; ++k4) {
        const float4 wv = Wr[k4];
        const float4 hv = *(const float4*)&tht[k4 * 4];
        acc += wv.x * hv.x + wv.y * hv.y + wv.z * hv.z + wv.w * hv.w;
      }
      tgb[tid] = acc;
      __syncthreads();
      if (tid < HDIM) {
        const float cn =
            sigm(tgb[64 + tid]) * ct + sigm(tgb[tid]) * tanh_(tgb[128 + tid]);
        ct = cn;
        tht[tid] = sigm(tgb[192 + tid]) * tanh_(cn);
      }
      __syncthreads();
    }
    if (tid < HDIM) ht_out[tid] = tht[tid];
    return;
  }

  const int l = tid & 63;
  const int w = tid >> 6;   // wave id 0..3 -> owns gate-col slice w*16..w*16+15
  const int t15 = l & 15;
  const int g4 = l >> 4;
  const int n0 = blockIdx.x * NPB;

  // stage xo for this block's 16 neighbors, all steps (coalesced, no tail)
  for (int i = tid; i < OBS * NPB * 2; i += 256) {
    ((float*)xs)[i] = oth[(i >> 5) * (NTOT * 2) + n0 * 2 + (i & 31)];
  }
  // zero h buffer 0
  for (int i = tid; i < NPB * HDIM / 2; i += 256) ((unsigned int*)h2[0])[i] = 0u;

  // persistent B fragments: W_hh^T slices for this wave's gate cols,
  // RNE hi/lo split (W near-exact => no correlated-across-neighbor W error)
  short8 Bhi0, Bhi1, Bhi2, Bhi3, Bhi4, Bhi5, Bhi6, Bhi7;
  short8 Blo0, Blo1, Blo2, Blo3, Blo4, Blo5, Blo6, Blo7;
  float bias2[4], wih0[4], wih1[4];
#define LOADB(q, kt, BH, BL)                                        \
  {                                                                 \
    const float* wp = &W_hh[(q * 64 + w * 16 + t15) * 64 + kt * 32 + g4 * 8]; \
    _Pragma("unroll") for (int j = 0; j < 8; ++j) {                 \
      float wv = wp[j];                                             \
      unsigned short hi = f2bf(wv);                                 \
      unsigned short lo = f2bf(wv - bf2f(hi));                      \
      BH[j] = (short)hi;                                            \
      BL[j] = (short)lo;                                            \
    }                                                               \
  }
  LOADB(0, 0, Bhi0, Blo0) LOADB(0, 1, Bhi1, Blo1)
  LOADB(1, 0, Bhi2, Blo2) LOADB(1, 1, Bhi3, Blo3)
  LOADB(2, 0, Bhi4, Blo4) LOADB(2, 1, Bhi5, Blo5)
  LOADB(3, 0, Bhi6, Blo6) LOADB(3, 1, Bhi7, Blo7)
#undef LOADB
#pragma unroll
  for (int q = 0; q < 4; ++q) {
    int g = q * 64 + w * 16 + t15;
    bias2[q] = b_ih[g] + b_hh[g];
    wih0[q] = W_ih[g * 2 + 0];
    wih1[q] = W_ih[g * 2 + 1];
  }

  f32x4 c = (f32x4){0.f, 0.f, 0.f, 0.f};
  const float refx = tgt[14 * 2 + 0];
  const float refy = tgt[14 * 2 + 1];

  __syncthreads();

  for (int t = 0; t < OBS; ++t) {
    const int cur = t & 1, nxt = cur ^ 1;
    // A fragments: row t15, k-block (kt*4 + g4), direct bf16 LDS read
    short8 A0 = *(const short8*)&h2[cur][0][hidx(t15, g4)];
    short8 A1 = *(const short8*)&h2[cur][0][hidx(t15, 4 + g4)];

    f32x4 acc0, acc1, acc2, acc3;
#pragma unroll
    for (int r = 0; r < 4; ++r) {
      int nl = g4 * 4 + r;
      float xa = xs[t][nl][0], xb = xs[t][nl][1];
      acc0[r] = bias2[0] + xa * wih0[0] + xb * wih1[0];
      acc1[r] = bias2[1] + xa * wih0[1] + xb * wih1[1];
      acc2[r] = bias2[2] + xa * wih0[2] + xb * wih1[2];
      acc3[r] = bias2[3] + xa * wih0[3] + xb * wih1[3];
    }
    acc0 = MFMA_BF16(A0, Bhi0, acc0, 0, 0, 0);
    acc1 = MFMA_BF16(A0, Bhi2, acc1, 0, 0, 0);
    acc2 = MFMA_BF16(A0, Bhi4, acc2, 0, 0, 0);
    acc3 = MFMA_BF16(A0, Bhi6, acc3, 0, 0, 0);
    acc0 = MFMA_BF16(A1, Bhi1, acc0, 0, 0, 0);
    acc1 = MFMA_BF16(A1, Bhi3, acc1, 0, 0, 0);
    acc2 = MFMA_BF16(A1, Bhi5, acc2, 0, 0, 0);
    acc3 = MFMA_BF16(A1, Bhi7, acc3, 0, 0, 0);
    acc0 = MFMA_BF16(A0, Blo0, acc0, 0, 0, 0);
    acc1 = MFMA_BF16(A0, Blo2, acc1, 0, 0, 0);
    acc2 = MFMA_BF16(A0, Blo4, acc2, 0, 0, 0);
    acc3 = MFMA_BF16(A0, Blo6, acc3, 0, 0, 0);
    acc0 = MFMA_BF16(A1, Blo1, acc0, 0, 0, 0);
    acc1 = MFMA_BF16(A1, Blo3, acc1, 0, 0, 0);
    acc2 = MFMA_BF16(A1, Blo5, acc2, 0, 0, 0);
    acc3 = MFMA_BF16(A1, Blo7, acc3, 0, 0, 0);

    if (t < OBS - 1) {
#pragma unroll
      for (int r = 0; r < 4; ++r) {
        float si = sigm(acc0[r]);
        float sf = sigm(acc1[r]);
        float tg = tanh_(acc2[r]);
        float so = sigm(acc3[r]);
        float cn = sf * c[r] + si * tg;
        c[r] = cn;
        float h = so * tanh_(cn);
        int n = g4 * 4 + r;
        int col = w * 16 + t15;
        h2[nxt][0][hidx(n, col >> 3) + (col & 7)] = f2bf(h);
      }
      __syncthreads();
    } else {
      // final step: compute h (fp32) and pool directly
#pragma unroll
      for (int r = 0; r < 4; ++r) {
        float si = sigm(acc0[r]);
        float sf = sigm(acc1[r]);
        float tg = tanh_(acc2[r]);
        float so = sigm(acc3[r]);
        float cn = sf * c[r] + si * tg;
        float h = so * tanh_(cn);
        int nl = g4 * 4 + r;
        int gn = n0 + nl;
        float rx = xs[OBS - 1][nl][0] - refx;
        float ry = xs[OBS - 1][nl][1] - refy;
        bool within = (fabsf(rx) <= 2.0f) && (fabsf(ry) <= 2.0f);
        int cx = (int)truncf(rx) + 2;  // cw == 1.0
        int cy = (int)truncf(ry) + 2;
        bool valid = within && (cx >= 0) && (cx < 4) && (cy >= 0) && (cy < 4);
        if (valid) {
          if (mask[(OBS - 1) * NTOT + gn] != 0)
            atomicAdd(&social[(cy * 4 + cx) * HDIM + w * 16 + t15], h);
        }
      }
    }
  }
}

// Slim k_final (verified in rounds 1-2): social MLP + readout only.
__global__ __launch_bounds__(512) void k_final(
    const float* __restrict__ W1, const float* __restrict__ b1,
    const float* __restrict__ W2, const float* __restrict__ b2,
    const float* __restrict__ Wc, const float* __restrict__ bc,
    const float* __restrict__ social, const float* __restrict__ ht_g,
    float* __restrict__ out)
{
  __shared__ float sv[1024];
  __shared__ float hid[64];
  __shared__ float comb[64];
  __shared__ float ht[64];

  const int tid = threadIdx.x;
  for (int i = tid; i < 1024; i += 512) sv[i] = social[i];
  if (tid < 64) ht[tid] = ht_g[tid];
  __syncthreads();

  const int wv = tid >> 6, ln = tid & 63;
  for (int o = wv; o < 64; o += 8) {
    float p = 0.0f;
#pragma unroll
    for (int it = 0; it < 16; ++it) {
      const int j = it * 64 + ln;
      p += sv[j] * W1[o * 1024 + j];
    }
#pragma unroll
    for (int off = 32; off > 0; off >>= 1) p += __shfl_down(p, off);
    if (ln == 0) hid[o] = fmaxf(p + b1[o], 0.0f);
  }
  __syncthreads();
  for (int o = wv; o < 64; o += 8) {
    float p = hid[ln] * W2[o * 64 + ln];
#pragma unroll
    for (int off = 32; off > 0; off >>= 1) p += __shfl_down(p, off);
    if (ln == 0) comb[o] = ht[o] + p + b2[o];
  }
  __syncthreads();
  if (wv < 2) {
    float p = comb[ln] * Wc[wv * 64 + ln];
#pragma unroll
    for (int off = 32; off > 0; off >>= 1) p += __shfl_down(p, off);
    if (ln == 0) out[wv] = p + bc[wv];
  }
}

extern "C" void kernel_launch(void* const* d_in, const int* in_sizes, int n_in,
                              void* d_out, int out_size, void* d_ws, size_t ws_size,
                              hipStream_t stream) {
  const float* tgt = (const float*)d_in[0];
  const float* oth = (const float*)d_in[1];
  const int* mask = (const int*)d_in[2];
  const float* W_ih = (const float*)d_in[3];
  const float* b_ih = (const float*)d_in[4];
  const float* W_hh = (const float*)d_in[5];
  const float* b_hh = (const float*)d_in[6];
  const float* W1 = (const float*)d_in[7];
  const float* b1 = (const float*)d_in[8];
  const float* W2 = (const float*)d_in[9];
  const float* b2 = (const float*)d_in[10];
  const float* Wc = (const float*)d_in[11];
  const float* bc = (const float*)d_in[12];
  float* social = (float*)d_ws;          // ws[0..1023]
  float* ht = social + 1024;             // ws[1024..1087] (target-LSTM h)
  float* out = (float*)d_out;

  hipLaunchKernelGGL(k_zero, dim3(1), dim3(1024), 0, stream, social);
  hipLaunchKernelGGL(k_neigh, dim3(NBLK_N + 1), dim3(256), 0, stream,
                     tgt, oth, mask, W_ih, b_ih, W_hh, b_hh, social, ht);
  hipLaunchKernelGGL(k_final, dim3(1), dim3(512), 0, stream,
                     W1, b1, W2, b2, Wc, bc, social, ht, out);
}

// Round 4
// 126.093 us; speedup vs baseline: 2.9410x; 1.0990x over previous
//
#include <hip/hip_runtime.h>
#include <stdint.h>

#define OBS 15
#define NTOT 50000
#define HDIM 64
#define NPB 16               // neighbors per block (50000 = 3125 * 16, exact)
#define NBLK_N 3125          // neighbor blocks; blockIdx 0 runs the target LSTM
#define ZOFF (OBS * NPB * 8) // ushort index of the 16B zero slot in xbf

typedef __attribute__((ext_vector_type(8))) short short8;
typedef __attribute__((ext_vector_type(4))) float f32x4;
typedef __attribute__((ext_vector_type(4))) unsigned int u32x4;

static __device__ __forceinline__ unsigned short f2bf(float f) {
  unsigned u = __float_as_uint(f);
  u += 0x7fff + ((u >> 16) & 1);
  return (unsigned short)(u >> 16);
}
static __device__ __forceinline__ float bf2f(unsigned short b) {
  return __uint_as_float(((unsigned)b) << 16);
}

#if __has_builtin(__builtin_amdgcn_exp2f)
#define EXP2F(x) __builtin_amdgcn_exp2f(x)
#else
#define EXP2F(x) exp2f(x)
#endif
#if __has_builtin(__builtin_amdgcn_rcpf)
#define RCPF(x) __builtin_amdgcn_rcpf(x)
#else
#define RCPF(x) (1.0f / (x))
#endif

static __device__ __forceinline__ float sigm(float x) {
  return RCPF(1.0f + EXP2F(-1.4426950408889634f * x));
}
static __device__ __forceinline__ float tanh_(float x) {
  return 2.0f * RCPF(1.0f + EXP2F(-2.8853900817779268f * x)) - 1.0f;
}

// LDS ushort index: row r (0..15), 8-ushort block cb (0..7), swizzled.
static __device__ __forceinline__ int hidx(int r, int cb) {
  return r * 64 + ((cb ^ (r & 7)) << 3);
}

__global__ void k_zero(float* social) {
  social[threadIdx.x] = 0.0f;  // 1024 threads == 16*64 floats
}

#define MFMA_BF16 __builtin_amdgcn_mfma_f32_16x16x32_bf16

// ROUND-0 PROVEN INNER LOOP (118.5 us) with two independently-verified grafts:
//  (a) target LSTM block is blockIdx 0 (round 3 had it LAST -> its ~5-8 us
//      serial run extended the kernel tail; k_neigh 118.5->127.2).
//  (b) x*W_ih + bias folded into one MFMA per gate quadrant via the hi/lo
//      xbf table (k-slot pairing byte-identical to rounds 1-2, which passed
//      absmax 0.0): replaces 48 VALU FMAs + 8 LDS x-reads per wave-step with
//      1 ds_read_b128 + 4 MFMAs.
// Rounds 1-2 lesson: the transposed-MFMA structure (not the x-fold) caused the
// 3x regression — the x-fold is grafted WITHOUT touching the r0 MFMA/LDS/
// barrier structure.
// launch_bounds(256, 2): min 2 waves/EU -> 256-VGPR budget. (256,4) pins
// arch-VGPRs to 64 and spills the 64-reg B-fragment set (earlier rounds).
__global__ __launch_bounds__(256, 2)
void k_neigh(
    const float* __restrict__ tgt,   // 15*1*2
    const float* __restrict__ oth,   // 15*N*2
    const int* __restrict__ mask,    // 15*N
    const float* __restrict__ W_ih,  // 256*2
    const float* __restrict__ b_ih,  // 256
    const float* __restrict__ W_hh,  // 256*64
    const float* __restrict__ b_hh,  // 256
    float* __restrict__ social,      // 16*64, pre-zeroed
    float* __restrict__ ht_out)      // 64 (target-LSTM final h)
{
  __shared__ __align__(16) unsigned short h2[2][NPB][HDIM];  // h as bf16
  // per (t,n): 8 ushorts {x0hi,x0hi,x0lo,x1hi,x1hi,x1lo,1,1} + 16B zero slot
  __shared__ __align__(16) unsigned short xbf[ZOFF + 8];
  __shared__ float xs14[NPB][2];
  __shared__ float tht[HDIM];
  __shared__ float tgb[256];

  const int tid = threadIdx.x;

  if (blockIdx.x == 0) {
    // ---- target LSTM, fp32 exact; dispatched FIRST so it hides under the
    // neighbor grid's ramp.  Block-uniform branch; all threads hit barriers.
    const float bias = b_ih[tid] + b_hh[tid];
    const float wi0 = W_ih[tid * 2], wi1 = W_ih[tid * 2 + 1];
    const float4* Wr = (const float4*)&W_hh[tid * 64];
    if (tid < HDIM) tht[tid] = 0.0f;
    float ct = 0.0f;
    __syncthreads();
    for (int t = 0; t < OBS; ++t) {
      const float x0 = tgt[t * 2], x1 = tgt[t * 2 + 1];
      float acc = bias + x0 * wi0 + x1 * wi1;
      // unroll 4 keeps this region's VGPR demand below the main path's
#pragma unroll 4
      for (int k4 = 0; k4 < 16; ++k4) {
        const float4 wv = Wr[k4];
        const float4 hv = *(const float4*)&tht[k4 * 4];
        acc += wv.x * hv.x + wv.y * hv.y + wv.z * hv.z + wv.w * hv.w;
      }
      tgb[tid] = acc;
      __syncthreads();
      if (tid < HDIM) {
        const float cn =
            sigm(tgb[64 + tid]) * ct + sigm(tgb[tid]) * tanh_(tgb[128 + tid]);
        ct = cn;
        tht[tid] = sigm(tgb[192 + tid]) * tanh_(cn);
      }
      __syncthreads();
    }
    if (tid < HDIM) ht_out[tid] = tht[tid];
    return;
  }

  const int l = tid & 63;
  const int w = tid >> 6;   // wave id 0..3 -> owns gate-col slice w*16..w*16+15
  const int t15 = l & 15;
  const int g4 = l >> 4;
  const int n0 = (blockIdx.x - 1) * NPB;

  // ---- stage x hi/lo MFMA table + last-step raw positions (240 items) ----
  if (tid < OBS * NPB) {
    const int t = tid >> 4, n = tid & 15;
    const int gn = n0 + n;
    const float x0 = oth[(t * NTOT + gn) * 2 + 0];
    const float x1 = oth[(t * NTOT + gn) * 2 + 1];
    const unsigned short xh0 = f2bf(x0);
    const unsigned short xl0 = f2bf(x0 - bf2f(xh0));
    const unsigned short xh1 = f2bf(x1);
    const unsigned short xl1 = f2bf(x1 - bf2f(xh1));
    u32x4 d;
    d.x = (unsigned)xh0 | ((unsigned)xh0 << 16);  // k0=x0hi k1=x0hi
    d.y = (unsigned)xl0 | ((unsigned)xh1 << 16);  // k2=x0lo k3=x1hi
    d.z = (unsigned)xh1 | ((unsigned)xl1 << 16);  // k4=x1hi k5=x1lo
    d.w = 0x3F803F80u;                            // k6=1    k7=1
    *(u32x4*)&xbf[tid * 8] = d;
    if (t == OBS - 1) { xs14[n][0] = x0; xs14[n][1] = x1; }
  }
  if (tid == 255) {
    u32x4 zz = {0u, 0u, 0u, 0u};
    *(u32x4*)&xbf[ZOFF] = zz;
  }
  // zero h buffer 0
  for (int i = tid; i < NPB * HDIM / 2; i += 256) ((unsigned int*)h2[0])[i] = 0u;

  // persistent B fragments: W_hh^T slices for this wave's gate cols,
  // RNE hi/lo split (proven indexing)
  short8 Bhi0, Bhi1, Bhi2, Bhi3, Bhi4, Bhi5, Bhi6, Bhi7;
  short8 Blo0, Blo1, Blo2, Blo3, Blo4, Blo5, Blo6, Blo7;
#define LOADB(q, kt, BH, BL)                                        \
  {                                                                 \
    const float* wp = &W_hh[(q * 64 + w * 16 + t15) * 64 + kt * 32 + g4 * 8]; \
    _Pragma("unroll") for (int j = 0; j < 8; ++j) {                 \
      float wv = wp[j];                                             \
      unsigned short hi = f2bf(wv);                                 \
      unsigned short lo = f2bf(wv - bf2f(hi));                      \
      BH[j] = (short)hi;                                            \
      BL[j] = (short)lo;                                            \
    }                                                               \
  }
  LOADB(0, 0, Bhi0, Blo0) LOADB(0, 1, Bhi1, Blo1)
  LOADB(1, 0, Bhi2, Blo2) LOADB(1, 1, Bhi3, Blo3)
  LOADB(2, 0, Bhi4, Blo4) LOADB(2, 1, Bhi5, Blo5)
  LOADB(3, 0, Bhi6, Blo6) LOADB(3, 1, Bhi7, Blo7)
#undef LOADB

  // ---- B_x fragments: W_ih + bias as MFMA B-operand, one per quadrant.
  // Col = t15 (gate q*64+w*16+t15), k-slots pair with the xbf row layout:
  // k0=w0hi k1=w0lo k2=w0hi k3=w1hi k4=w1lo k5=w1hi k6=bias_hi k7=bias_lo.
  // Dot vs {x0hi,x0hi,x0lo,x1hi,x1hi,x1lo,1,1} = w0*x0 + w1*x1 + bias
  // (hi*hi + hi*lo + lo*hi each) — byte-identical arithmetic to rounds 1-2.
  short8 BX0, BX1, BX2, BX3;
  {
    u32x4 z4 = {0u, 0u, 0u, 0u};
    BX0 = BX1 = BX2 = BX3 = __builtin_bit_cast(short8, z4);
    if (g4 == 0) {
#pragma unroll
      for (int q = 0; q < 4; ++q) {
        const int G = q * 64 + w * 16 + t15;
        const float w0 = W_ih[G * 2 + 0], w1 = W_ih[G * 2 + 1];
        const float bs = b_ih[G] + b_hh[G];
        const unsigned short w0h = f2bf(w0), w0l = f2bf(w0 - bf2f(w0h));
        const unsigned short w1h = f2bf(w1), w1l = f2bf(w1 - bf2f(w1h));
        const unsigned short bh = f2bf(bs), bl = f2bf(bs - bf2f(bh));
        u32x4 d;
        d.x = (unsigned)w0h | ((unsigned)w0l << 16);
        d.y = (unsigned)w0h | ((unsigned)w1h << 16);
        d.z = (unsigned)w1l | ((unsigned)w1h << 16);
        d.w = (unsigned)bh | ((unsigned)bl << 16);
        const short8 v = __builtin_bit_cast(short8, d);
        if (q == 0) BX0 = v;
        else if (q == 1) BX1 = v;
        else if (q == 2) BX2 = v;
        else BX3 = v;
      }
    }
  }

  // A_x read offset: g4==0 lanes walk the xbf table, others broadcast-read
  // the zero slot (uniform address -> no conflict).
  int xo = (g4 == 0) ? (t15 * 8) : ZOFF;
  const int xst = (g4 == 0) ? (NPB * 8) : 0;

  f32x4 c = (f32x4){0.f, 0.f, 0.f, 0.f};
  const float refx = tgt[14 * 2 + 0];
  const float refy = tgt[14 * 2 + 1];

  __syncthreads();

  for (int t = 0; t < OBS; ++t) {
    const int cur = t & 1, nxt = cur ^ 1;
    // A_x fragment first (chain head), then h A-fragments
    const short8 Ax = *(const short8*)&xbf[xo];
    short8 A0 = *(const short8*)&h2[cur][0][hidx(t15, g4)];
    short8 A1 = *(const short8*)&h2[cur][0][hidx(t15, 4 + g4)];
    xo += xst;

    const f32x4 z = (f32x4){0.f, 0.f, 0.f, 0.f};
    f32x4 acc0 = MFMA_BF16(Ax, BX0, z, 0, 0, 0);
    f32x4 acc1 = MFMA_BF16(Ax, BX1, z, 0, 0, 0);
    f32x4 acc2 = MFMA_BF16(Ax, BX2, z, 0, 0, 0);
    f32x4 acc3 = MFMA_BF16(Ax, BX3, z, 0, 0, 0);
    acc0 = MFMA_BF16(A0, Bhi0, acc0, 0, 0, 0);
    acc1 = MFMA_BF16(A0, Bhi2, acc1, 0, 0, 0);
    acc2 = MFMA_BF16(A0, Bhi4, acc2, 0, 0, 0);
    acc3 = MFMA_BF16(A0, Bhi6, acc3, 0, 0, 0);
    acc0 = MFMA_BF16(A1, Bhi1, acc0, 0, 0, 0);
    acc1 = MFMA_BF16(A1, Bhi3, acc1, 0, 0, 0);
    acc2 = MFMA_BF16(A1, Bhi5, acc2, 0, 0, 0);
    acc3 = MFMA_BF16(A1, Bhi7, acc3, 0, 0, 0);
    acc0 = MFMA_BF16(A0, Blo0, acc0, 0, 0, 0);
    acc1 = MFMA_BF16(A0, Blo2, acc1, 0, 0, 0);
    acc2 = MFMA_BF16(A0, Blo4, acc2, 0, 0, 0);
    acc3 = MFMA_BF16(A0, Blo6, acc3, 0, 0, 0);
    acc0 = MFMA_BF16(A1, Blo1, acc0, 0, 0, 0);
    acc1 = MFMA_BF16(A1, Blo3, acc1, 0, 0, 0);
    acc2 = MFMA_BF16(A1, Blo5, acc2, 0, 0, 0);
    acc3 = MFMA_BF16(A1, Blo7, acc3, 0, 0, 0);

    if (t < OBS - 1) {
#pragma unroll
      for (int r = 0; r < 4; ++r) {
        float si = sigm(acc0[r]);
        float sf = sigm(acc1[r]);
        float tg = tanh_(acc2[r]);
        float so = sigm(acc3[r]);
        float cn = sf * c[r] + si * tg;
        c[r] = cn;
        float h = so * tanh_(cn);
        int n = g4 * 4 + r;
        int col = w * 16 + t15;
        h2[nxt][0][hidx(n, col >> 3) + (col & 7)] = f2bf(h);
      }
      __syncthreads();
    } else {
      // final step: compute h (fp32) and pool directly
#pragma unroll
      for (int r = 0; r < 4; ++r) {
        float si = sigm(acc0[r]);
        float sf = sigm(acc1[r]);
        float tg = tanh_(acc2[r]);
        float so = sigm(acc3[r]);
        float cn = sf * c[r] + si * tg;
        float h = so * tanh_(cn);
        int nl = g4 * 4 + r;
        int gn = n0 + nl;
        float rx = xs14[nl][0] - refx;
        float ry = xs14[nl][1] - refy;
        bool within = (fabsf(rx) <= 2.0f) && (fabsf(ry) <= 2.0f);
        int cx = (int)truncf(rx) + 2;  // cw == 1.0
        int cy = (int)truncf(ry) + 2;
        bool valid = within && (cx >= 0) && (cx < 4) && (cy >= 0) && (cy < 4);
        if (valid) {
          if (mask[(OBS - 1) * NTOT + gn] != 0)
            atomicAdd(&social[(cy * 4 + cx) * HDIM + w * 16 + t15], h);
        }
      }
    }
  }
}

// Slim k_final (verified in rounds 1-3): social MLP + readout only.
__global__ __launch_bounds__(512) void k_final(
    const float* __restrict__ W1, const float* __restrict__ b1,
    const float* __restrict__ W2, const float* __restrict__ b2,
    const float* __restrict__ Wc, const float* __restrict__ bc,
    const float* __restrict__ social, const float* __restrict__ ht_g,
    float* __restrict__ out)
{
  __shared__ float sv[1024];
  __shared__ float hid[64];
  __shared__ float comb[64];
  __shared__ float ht[64];

  const int tid = threadIdx.x;
  for (int i = tid; i < 1024; i += 512) sv[i] = social[i];
  if (tid < 64) ht[tid] = ht_g[tid];
  __syncthreads();

  const int wv = tid >> 6, ln = tid & 63;
  for (int o = wv; o < 64; o += 8) {
    float p = 0.0f;
#pragma unroll
    for (int it = 0; it < 16; ++it) {
      const int j = it * 64 + ln;
      p += sv[j] * W1[o * 1024 + j];
    }
#pragma unroll
    for (int off = 32; off > 0; off >>= 1) p += __shfl_down(p, off);
    if (ln == 0) hid[o] = fmaxf(p + b1[o], 0.0f);
  }
  __syncthreads();
  for (int o = wv; o < 64; o += 8) {
    float p = hid[ln] * W2[o * 64 + ln];
#pragma unroll
    for (int off = 32; off > 0; off >>= 1) p += __shfl_down(p, off);
    if (ln == 0) comb[o] = ht[o] + p + b2[o];
  }
  __syncthreads();
  if (wv < 2) {
    float p = comb[ln] * Wc[wv * 64 + ln];
#pragma unroll
    for (int off = 32; off > 0; off >>= 1) p += __shfl_down(p, off);
    if (ln == 0) out[wv] = p + bc[wv];
  }
}

extern "C" void kernel_launch(void* const* d_in, const int* in_sizes, int n_in,
                              void* d_out, int out_size, void* d_ws, size_t ws_size,
                              hipStream_t stream) {
  const float* tgt = (const float*)d_in[0];
  const float* oth = (const float*)d_in[1];
  const int* mask = (const int*)d_in[2];
  const float* W_ih = (const float*)d_in[3];
  const float* b_ih = (const float*)d_in[4];
  const float* W_hh = (const float*)d_in[5];
  const float* b_hh = (const float*)d_in[6];
  const float* W1 = (const float*)d_in[7];
  const float* b1 = (const float*)d_in[8];
  const float* W2 = (const float*)d_in[9];
  const float* b2 = (const float*)d_in[10];
  const float* Wc = (const float*)d_in[11];
  const float* bc = (const float*)d_in[12];
  float* social = (float*)d_ws;          // ws[0..1023]
  float* ht = social + 1024;             // ws[1024..1087] (target-LSTM h)
  float* out = (float*)d_out;

  hipLaunchKernelGGL(k_zero, dim3(1), dim3(1024), 0, stream, social);
  hipLaunchKernelGGL(k_neigh, dim3(NBLK_N + 1), dim3(256), 0, stream,
                     tgt, oth, mask, W_ih, b_ih, W_hh, b_hh, social, ht);
  hipLaunchKernelGGL(k_final, dim3(1), dim3(512), 0, stream,
                     W1, b1, W2, b2, Wc, bc, social, ht, out);
}